// Round 1
// 872.963 us; speedup vs baseline: 1.0122x; 1.0122x over previous
//
#include <hip/hip_runtime.h>
#include <math.h>

// Bahdanau attention, fp32: B=65536, W=20, E=128.
// v3: rolled loop + depth-1 register prefetch (occupancy >> unroll-20 VGPR bloat),
//     DPP row_ror rotate-reduce (no ds_bpermute), XOR-swizzled LDS (2-way max),
//     log2-domain softmax with fixed reference + rare rescale, algebraic folds:
//       rq' = q*W1*2log2e;  lw3 scaled by -2log2e;  A0 = log2e*rowsum(W3)/16
//     => per element: mul, mul, exp2, add, rcp, fma  (4 VALU + 2 trans)

#define NB 65536
#define NW 20
#define NE 128
#define LOG2E 1.4426950408889634f

// DPP rotate-right-by-k within each 16-lane row + add (pure VALU, no LDS pipe).
// row_ror:k = 0x120 + k
template <int CTRL>
__device__ __forceinline__ float row_ror_add(float x) {
    int y = __builtin_amdgcn_update_dpp(0, __float_as_int(x), CTRL, 0xF, 0xF, true);
    return x + __int_as_float(y);
}

__global__ __launch_bounds__(256, 6)
void bahdanau_kernel(const float* __restrict__ query,
                     const float* __restrict__ value,
                     const float* __restrict__ W1,
                     const float* __restrict__ W2,
                     const float* __restrict__ W3,
                     float* __restrict__ out) {
    // W2/W3 staged to LDS as float4, XOR-swizzled within each 32-float4 row:
    // slot j = i ^ ((i>>3)&3). Read pattern (lane l16 reads float4s 2*l16, 2*l16+1)
    // then lands in every bank-group at most 2x -> conflict-free in practice (m136).
    __shared__ __align__(16) float4 lw2[NW * NE / 4];   // 10 KB
    __shared__ __align__(16) float4 lw3[NW * NE / 4];   // 10 KB (scaled by -2*log2e)
    __shared__ float pw3[NW * 8];
    __shared__ float w3s16[NW];                         // log2e * rowsum(W3) / 16

    const float4* W2v = (const float4*)W2;
    const float4* W3v = (const float4*)W3;
    const float S3 = -2.0f * LOG2E;
    for (int i = threadIdx.x; i < NW * NE / 4; i += 256) {
        int j = i ^ ((i >> 3) & 3);          // bits 3..4 are within-row chunk id
        lw2[j] = W2v[i];
        float4 t = W3v[i];
        t.x *= S3; t.y *= S3; t.z *= S3; t.w *= S3;
        lw3[j] = t;
    }
    // W3 row sums (raw, from global: L1/L2-hot, one-time)
    if (threadIdx.x < NW * 8) {
        int w = threadIdx.x >> 3, j = threadIdx.x & 7;
        const float4* p = W3v + w * 32 + j * 4;
        float4 a = p[0], b = p[1], c = p[2], d = p[3];
        pw3[threadIdx.x] = ((a.x + a.y) + (a.z + a.w)) + ((b.x + b.y) + (b.z + b.w))
                         + ((c.x + c.y) + (c.z + c.w)) + ((d.x + d.y) + (d.z + d.w));
    }
    __syncthreads();
    if (threadIdx.x < NW) {
        const float* q = pw3 + threadIdx.x * 8;
        float sum = ((q[0] + q[1]) + (q[2] + q[3])) + ((q[4] + q[5]) + (q[6] + q[7]));
        w3s16[threadIdx.x] = sum * (LOG2E / 16.0f);
    }
    __syncthreads();

    const int lane = threadIdx.x & 63;
    const int wave = threadIdx.x >> 6;
    const int grp  = lane >> 4;        // which of 4 b's in this wave
    const int l16  = lane & 15;        // lane within the 16-lane group
    const int b    = blockIdx.x * 16 + wave * 4 + grp;
    const int e0   = l16 * 8;          // this lane's 8 elements

    // swizzled within-row float4 indices for this lane
    const int c4 = (l16 >> 2) & 3;
    const int f0 = (2 * l16) ^ c4;
    const int f1 = (2 * l16 + 1) ^ c4;

    // rq' = q * W1 * 2*log2(e): folds tanh's 2x and the e->2 base change into one constant
    const float* qp = query + (size_t)b * NE + e0;
    float4 qa = *(const float4*)(qp);
    float4 qb = *(const float4*)(qp + 4);
    float4 w1a = *(const float4*)(W1 + e0);
    float4 w1b = *(const float4*)(W1 + e0 + 4);
    const float TS = 2.0f * LOG2E;
    float4 rqa, rqb;
    rqa.x = qa.x * w1a.x * TS; rqa.y = qa.y * w1a.y * TS;
    rqa.z = qa.z * w1a.z * TS; rqa.w = qa.w * w1a.w * TS;
    rqb.x = qb.x * w1b.x * TS; rqb.y = qb.y * w1b.y * TS;
    rqb.z = qb.z * w1b.z * TS; rqb.w = qb.w * w1b.w * TS;

    const float* vp = value + (size_t)b * (NW * NE) + e0;

    // r = 1/(1 + e^{2x}) with 2x*log2e prefolded into rq'. tanh(x) = 1 - 2r.
    auto relem = [](float rq_, float v_, float w2_) -> float {
        return __builtin_amdgcn_rcpf(1.0f + __builtin_amdgcn_exp2f(rq_ * v_ * w2_));
    };

    // returns score * log2e (log2-domain), identical in all 16 lanes of the group
    auto score_w = [&](int w, float4 va, float4 vb) -> float {
        const int o = w * 32;
        float4 w2a = lw2[o + f0], w2b = lw2[o + f1];
        float4 w3a = lw3[o + f0], w3b = lw3[o + f1];   // pre-scaled by -2*log2e
        float A1 = w3s16[w], A2 = 0.f;                 // A1 init: +log2e*rowsum(W3)/16
        A1 = fmaf(relem(rqa.x, va.x, w2a.x), w3a.x, A1);
        A2 = fmaf(relem(rqa.y, va.y, w2a.y), w3a.y, A2);
        A1 = fmaf(relem(rqa.z, va.z, w2a.z), w3a.z, A1);
        A2 = fmaf(relem(rqa.w, va.w, w2a.w), w3a.w, A2);
        A1 = fmaf(relem(rqb.x, vb.x, w2b.x), w3b.x, A1);
        A2 = fmaf(relem(rqb.y, vb.y, w2b.y), w3b.y, A2);
        A1 = fmaf(relem(rqb.z, vb.z, w2b.z), w3b.z, A1);
        A2 = fmaf(relem(rqb.w, vb.w, w2b.w), w3b.w, A2);
        float p = A1 + A2;
        p = row_ror_add<0x128>(p);   // ror 8
        p = row_ror_add<0x124>(p);   // ror 4
        p = row_ror_add<0x122>(p);   // ror 2
        p = row_ror_add<0x121>(p);   // ror 1
        return p;
    };

    // ---- iter 0 (peeled): pw = 1 exactly ----
    float4 va = *(const float4*)(vp);
    float4 vb = *(const float4*)(vp + 4);
    float4 pa = *(const float4*)(vp + NE);
    float4 pb = *(const float4*)(vp + NE + 4);

    float m = score_w(0, va, vb);   // fixed softmax reference (log2 domain)
    float s = 1.f;
    float4 ca = va, cb = vb;

    // ---- iters 1..19, depth-1 register prefetch ----
#pragma unroll 1
    for (int w = 1; w < NW; ++w) {
        va = pa; vb = pb;
        if (w + 1 < NW) {
            pa = *(const float4*)(vp + (w + 1) * NE);
            pb = *(const float4*)(vp + (w + 1) * NE + 4);
        }
        float sc = score_w(w, va, vb);
        float d = sc - m;
        // softmax is shift-invariant: only rescale when overflow threatens.
        // d <= 40 => pw <= 2^40, s <= 20*2^40, c <= ~2^48: safe in fp32.
        if (__builtin_expect(d > 40.f, 0)) {
            float g = __builtin_amdgcn_exp2f(-d);
            s *= g;
            ca.x *= g; ca.y *= g; ca.z *= g; ca.w *= g;
            cb.x *= g; cb.y *= g; cb.z *= g; cb.w *= g;
            m = sc; d = 0.f;
        }
        float pw = __builtin_amdgcn_exp2f(d);
        s += pw;
        ca.x = fmaf(pw, va.x, ca.x); ca.y = fmaf(pw, va.y, ca.y);
        ca.z = fmaf(pw, va.z, ca.z); ca.w = fmaf(pw, va.w, ca.w);
        cb.x = fmaf(pw, vb.x, cb.x); cb.y = fmaf(pw, vb.y, cb.y);
        cb.z = fmaf(pw, vb.z, cb.z); cb.w = fmaf(pw, vb.w, cb.w);
    }

    const float inv = __builtin_amdgcn_rcpf(s);
    float4 oa, ob;
    oa.x = ca.x * inv; oa.y = ca.y * inv; oa.z = ca.z * inv; oa.w = ca.w * inv;
    ob.x = cb.x * inv; ob.y = cb.y * inv; ob.z = cb.z * inv; ob.w = cb.w * inv;
    float* op = out + (size_t)b * NE + e0;
    *(float4*)(op)     = oa;
    *(float4*)(op + 4) = ob;
}

extern "C" void kernel_launch(void* const* d_in, const int* in_sizes, int n_in,
                              void* d_out, int out_size, void* d_ws, size_t ws_size,
                              hipStream_t stream) {
    const float* query = (const float*)d_in[0];
    const float* value = (const float*)d_in[1];
    const float* W1    = (const float*)d_in[2];
    const float* W2    = (const float*)d_in[3];
    const float* W3    = (const float*)d_in[4];
    float* out = (float*)d_out;

    // 16 b per block (4 waves x 4 groups) -> exactly 4096 blocks
    dim3 grid(NB / 16), block(256);
    hipLaunchKernelGGL(bahdanau_kernel, grid, block, 0, stream,
                       query, value, W1, W2, W3, out);
}